// Round 2
// baseline (56.338 us; speedup 1.0000x reference)
//
#include <hip/hip_runtime.h>
#include <math.h>

// x[32,3,512,512] f32 -> |1 - mean over (b,h,w) of min over (c, 20x20 window,
// replicate pad pl=9 pr=10)|.
//
// Single fused tiled kernel (64x64 outputs/block):
//   step 1: channel-min tile staged to LDS via aligned float4 loads
//           (cm covers global cols [w0-12, w0+76), rows [h0-9, h0+74))
//   step 2: horizontal sliding-min window 20, Gil-Werman runs of 8 outputs
//   step 3: vertical sliding-min window 20, Gil-Werman runs of 16 outputs,
//           accumulate into block partial sums
//   step 4: tiny deterministic reduce kernel.

#define BATCH 32
#define HH 512
#define WW 512
#define KWIN 20
#define TH 64
#define TW 64
#define IH (TH + KWIN - 1)    // 83 rows staged
#define CMW 88                // cm width/stride (cols w0-12 .. w0+75, 16B aligned)
#define NQ 22                 // float4 quads per cm row

__device__ __forceinline__ float fmin3(float a, float b, float c) {
    return fminf(fminf(a, b), c);
}

__launch_bounds__(256)
__global__ void dark_tile_kernel(const float* __restrict__ x,
                                 float* __restrict__ partials)
{
    __shared__ float cm[IH * CMW];   // 83*88*4 = 29216 B
    __shared__ float hm[IH * TW];    // 83*64*4 = 21248 B
    __shared__ float red[4];

    const int b  = blockIdx.z;
    const int h0 = blockIdx.y * TH;
    const int w0 = blockIdx.x * TW;
    const int t  = threadIdx.x;
    const int CH = HH * WW;

    const float* xb = x + (size_t)b * 3 * CH;

    // ---- Step 1: channel-min into cm via aligned float4 loads ----
    // cm[r][c] = min_c x[gr(r)][w0-12+c], rows/cols clamped (== replicate pad)
    for (int task = t; task < IH * NQ; task += 256) {
        int r = task / NQ;
        int q = task - r * NQ;
        int gr = h0 - 9 + r; gr = gr < 0 ? 0 : (gr > HH - 1 ? HH - 1 : gr);
        int gb = w0 - 12 + (q << 2);
        const float* rowp = xb + gr * WW;
        float4 m;
        if (gb >= 0 && gb + 3 < WW) {
            float4 a0 = *(const float4*)(rowp + gb);
            float4 a1 = *(const float4*)(rowp + gb + CH);
            float4 a2 = *(const float4*)(rowp + gb + 2 * CH);
            m.x = fmin3(a0.x, a1.x, a2.x);
            m.y = fmin3(a0.y, a1.y, a2.y);
            m.z = fmin3(a0.z, a1.z, a2.z);
            m.w = fmin3(a0.w, a1.w, a2.w);
        } else {
            float mv[4];
            #pragma unroll
            for (int e = 0; e < 4; ++e) {
                int gc = gb + e; gc = gc < 0 ? 0 : (gc > WW - 1 ? WW - 1 : gc);
                mv[e] = fmin3(rowp[gc], rowp[gc + CH], rowp[gc + 2 * CH]);
            }
            m = make_float4(mv[0], mv[1], mv[2], mv[3]);
        }
        *(float4*)&cm[r * CMW + (q << 2)] = m;
    }
    __syncthreads();

    // ---- Step 2: horizontal min, runs of 8 outputs per task ----
    // output col j needs cm cols [j+3, j+22]; run j0..j0+7 needs [j0+3, j0+29]
    // load e[0..31] = cm[r][j0 .. j0+31] as 8 float4 (aligned)
    for (int task = t; task < IH * 8; task += 256) {
        int r  = task >> 3;
        int u  = task & 7;
        int j0 = u << 3;
        const float4* p = (const float4*)&cm[r * CMW + j0];
        float e[32];
        #pragma unroll
        for (int k = 0; k < 8; ++k) {
            float4 f = p[k];
            e[4 * k + 0] = f.x; e[4 * k + 1] = f.y;
            e[4 * k + 2] = f.z; e[4 * k + 3] = f.w;
        }
        // suf[i] = min(e[i+3 .. 19]) for i=0..16
        float suf[17];
        suf[16] = e[19];
        #pragma unroll
        for (int k = 15; k >= 0; --k) suf[k] = fminf(e[k + 3], suf[k + 1]);
        // pre[k] = min(e[20 .. 20+k]) for k=0..9
        float pre[10];
        pre[0] = e[20];
        #pragma unroll
        for (int k = 1; k < 10; ++k) pre[k] = fminf(pre[k - 1], e[20 + k]);
        // o[i] = min(e[i+3 .. i+22]) = min(suf[i], pre[i+2])
        float o[8];
        #pragma unroll
        for (int i = 0; i < 8; ++i) o[i] = fminf(suf[i], pre[i + 2]);
        *(float4*)&hm[r * TW + j0]     = make_float4(o[0], o[1], o[2], o[3]);
        *(float4*)&hm[r * TW + j0 + 4] = make_float4(o[4], o[5], o[6], o[7]);
    }
    __syncthreads();

    // ---- Step 3: vertical min, runs of 16 outputs per task (256 tasks) ----
    float sum = 0.f;
    {
        int j  = t & 63;
        int i0 = (t >> 6) << 4;
        float w[35];
        #pragma unroll
        for (int d = 0; d < 35; ++d) w[d] = hm[(i0 + d) * TW + j];
        // suf[i] = min(w[i .. 19]) for i=0..19 (need 0..15)
        float suf[20];
        suf[19] = w[19];
        #pragma unroll
        for (int k = 18; k >= 0; --k) suf[k] = fminf(w[k], suf[k + 1]);
        // pre[k] = min(w[20 .. 20+k]) for k=0..14
        float pre[15];
        pre[0] = w[20];
        #pragma unroll
        for (int k = 1; k < 15; ++k) pre[k] = fminf(pre[k - 1], w[20 + k]);
        sum += suf[0];                       // o_0 = min(w[0..19])
        #pragma unroll
        for (int i = 1; i < 16; ++i) sum += fminf(suf[i], pre[i - 1]);
    }

    // ---- Block reduction (deterministic) ----
    #pragma unroll
    for (int off = 32; off; off >>= 1) sum += __shfl_down(sum, off);
    if ((t & 63) == 0) red[t >> 6] = sum;
    __syncthreads();
    if (t == 0) {
        float ps = red[0] + red[1] + red[2] + red[3];
        int blockId = (blockIdx.z * gridDim.y + blockIdx.y) * gridDim.x + blockIdx.x;
        partials[blockId] = ps;
    }
}

__launch_bounds__(256)
__global__ void dark_reduce_kernel(const float* __restrict__ partials, int n,
                                   float* __restrict__ out)
{
    __shared__ float red[4];
    int t = threadIdx.x;
    float s = 0.f;
    for (int i = t; i < n; i += 256) s += partials[i];
    #pragma unroll
    for (int off = 32; off; off >>= 1) s += __shfl_down(s, off);
    if ((t & 63) == 0) red[t >> 6] = s;
    __syncthreads();
    if (t == 0) {
        float total = red[0] + red[1] + red[2] + red[3];
        float mean = total / (float)((long long)BATCH * HH * WW);
        out[0] = fabsf(1.0f - mean);
    }
}

extern "C" void kernel_launch(void* const* d_in, const int* in_sizes, int n_in,
                              void* d_out, int out_size, void* d_ws, size_t ws_size,
                              hipStream_t stream) {
    const float* x = (const float*)d_in[0];
    float* out = (float*)d_out;
    float* partials = (float*)d_ws;   // 2048 floats

    dim3 grid(WW / TW, HH / TH, BATCH);   // 8 x 8 x 32 = 2048 blocks
    dark_tile_kernel<<<grid, 256, 0, stream>>>(x, partials);
    dark_reduce_kernel<<<1, 256, 0, stream>>>(partials, (WW / TW) * (HH / TH) * BATCH, out);
}

// Round 4
// 36.322 us; speedup vs baseline: 1.5511x; 1.5511x over previous
//
#include <hip/hip_runtime.h>
#include <hip/hip_fp16.h>
#include <math.h>

// x[32,3,512,512] f32 -> |1 - mean over (b,h,w) of min over (c, 20x20 window,
// replicate pad pl=9 pr=10)|.
//
// Separable, barrier-free, LDS-free:
//   K1: channel-min + horizontal sliding-min(20), runs of 16 cols/thread,
//       vectorized float4 global reads, writes hm[32,512,512] f16 into d_ws.
//   K2: vertical sliding-min(20) on hm as packed f16x2 (v_pk_min_f16),
//       f32 accumulate -> per-block partials.
//   K3: deterministic reduce -> |1 - mean|.
//
// ROCm 7.2 gfx950 has no __hmin2 -> inline asm v_pk_min_f16 on uint-packed
// half2 values.

#define BATCH 32
#define HH 512
#define WW 512
#define CH (HH * WW)

__device__ __forceinline__ float fmin3(float a, float b, float c) {
    return fminf(fminf(a, b), c);
}

__device__ __forceinline__ unsigned pkmin(unsigned a, unsigned b) {
    unsigned r;
    asm volatile("v_pk_min_f16 %0, %1, %2" : "=v"(r) : "v"(a), "v"(b));
    return r;
}

__device__ __forceinline__ float2 unpack_h2(unsigned u) {
    __half2 h;
    *(unsigned*)&h = u;
    return __half22float2(h);
}

// ---------------- K1: horizontal pass ----------------
// thread -> (b, h, run): run = gid&31 (16 cols), h = (gid>>5)&511, b = gid>>14
__launch_bounds__(256)
__global__ void hmin_kernel(const float* __restrict__ x, __half* __restrict__ hm)
{
    int gid = blockIdx.x * 256 + threadIdx.x;
    int r = gid & 31;
    int h = (gid >> 5) & (HH - 1);
    int b = gid >> 14;
    int j0 = r << 4;

    const float* row = x + (size_t)b * 3 * CH + (size_t)h * WW;

    // Load 40 floats per channel from clamped aligned base, channel-min into e.
    int cb  = j0 - 12;
    int cbc = cb < 0 ? 0 : (cb > WW - 40 ? WW - 40 : cb);   // 0 or 472 at edges
    const float4* p0 = (const float4*)(row + cbc);
    const float4* p1 = (const float4*)(row + cbc + CH);
    const float4* p2 = (const float4*)(row + cbc + 2 * CH);
    float e[40];
    #pragma unroll
    for (int k = 0; k < 10; ++k) {
        float4 a = p0[k], bb = p1[k], c = p2[k];
        e[4 * k + 0] = fmin3(a.x, bb.x, c.x);
        e[4 * k + 1] = fmin3(a.y, bb.y, c.y);
        e[4 * k + 2] = fmin3(a.z, bb.z, c.z);
        e[4 * k + 3] = fmin3(a.w, bb.w, c.w);
    }

    // w[d] = channel-min at clamped col (j0 + d - 9), d = 0..34
    float w[35];
    if (r == 0) {
        #pragma unroll
        for (int d = 0; d < 35; ++d) w[d] = e[d < 9 ? 0 : d - 9];
    } else if (r == 31) {
        #pragma unroll
        for (int d = 0; d < 35; ++d) w[d] = e[d + 15 > 39 ? 39 : d + 15];
    } else {
        #pragma unroll
        for (int d = 0; d < 35; ++d) w[d] = e[d + 3];
    }

    // Gil-Werman: o[i] = min(w[i..i+19]), i = 0..15
    float suf[20];
    suf[19] = w[19];
    #pragma unroll
    for (int k = 18; k >= 0; --k) suf[k] = fminf(w[k], suf[k + 1]);
    float pre[15];
    pre[0] = w[20];
    #pragma unroll
    for (int k = 1; k < 15; ++k) pre[k] = fminf(pre[k - 1], w[20 + k]);
    float o[16];
    o[0] = suf[0];
    #pragma unroll
    for (int i = 1; i < 16; ++i) o[i] = fminf(suf[i], pre[i - 1]);

    // Pack to f16 and store 32 contiguous bytes.
    __half2 hp[8];
    #pragma unroll
    for (int k = 0; k < 8; ++k)
        hp[k] = __halves2half2(__float2half_rn(o[2 * k]), __float2half_rn(o[2 * k + 1]));
    float4* dst = (float4*)(hm + ((size_t)b * HH + h) * WW + j0);
    dst[0] = *(float4*)&hp[0];
    dst[1] = *(float4*)&hp[4];
}

// ---------------- K2: vertical pass + partial sums ----------------
// thread -> (b, rrun, jj): jj = gid&255 (half2 col pair), rrun = (gid>>8)&31
__launch_bounds__(256)
__global__ void vmin_kernel(const unsigned* __restrict__ hm2,
                            float* __restrict__ partials)
{
    int gid = blockIdx.x * 256 + threadIdx.x;
    int jj = gid & 255;
    int rr = (gid >> 8) & 31;
    int b  = gid >> 13;
    int i0 = rr << 4;

    const unsigned* col = hm2 + (size_t)b * (CH / 2) + jj;

    int rb  = i0 - 9;
    int rbc = rb < 0 ? 0 : (rb > HH - 35 ? HH - 35 : rb);   // 0 or 477 at edges
    unsigned ld[35];
    #pragma unroll
    for (int d = 0; d < 35; ++d) ld[d] = col[(rbc + d) * (WW / 2)];

    unsigned w[35];
    if (rr == 0) {
        #pragma unroll
        for (int d = 0; d < 35; ++d) w[d] = ld[d < 9 ? 0 : d - 9];
    } else if (rr == 31) {
        #pragma unroll
        for (int d = 0; d < 35; ++d) w[d] = ld[d + 10 > 34 ? 34 : d + 10];
    } else {
        #pragma unroll
        for (int d = 0; d < 35; ++d) w[d] = ld[d];
    }

    unsigned suf[20];
    suf[19] = w[19];
    #pragma unroll
    for (int k = 18; k >= 0; --k) suf[k] = pkmin(w[k], suf[k + 1]);
    unsigned pre[15];
    pre[0] = w[20];
    #pragma unroll
    for (int k = 1; k < 15; ++k) pre[k] = pkmin(pre[k - 1], w[20 + k]);

    float sum;
    {
        float2 f = unpack_h2(suf[0]);
        sum = f.x + f.y;
    }
    #pragma unroll
    for (int i = 1; i < 16; ++i) {
        float2 f = unpack_h2(pkmin(suf[i], pre[i - 1]));
        sum += f.x + f.y;
    }

    // deterministic block reduction
    #pragma unroll
    for (int off = 32; off; off >>= 1) sum += __shfl_down(sum, off);
    __shared__ float red[4];
    if ((threadIdx.x & 63) == 0) red[threadIdx.x >> 6] = sum;
    __syncthreads();
    if (threadIdx.x == 0)
        partials[blockIdx.x] = red[0] + red[1] + red[2] + red[3];
}

// ---------------- K3: final reduce ----------------
__launch_bounds__(256)
__global__ void dark_reduce_kernel(const float* __restrict__ partials, int n,
                                   float* __restrict__ out)
{
    __shared__ float red[4];
    int t = threadIdx.x;
    float s = 0.f;
    for (int i = t; i < n; i += 256) s += partials[i];
    #pragma unroll
    for (int off = 32; off; off >>= 1) s += __shfl_down(s, off);
    if ((t & 63) == 0) red[t >> 6] = s;
    __syncthreads();
    if (t == 0) {
        float total = red[0] + red[1] + red[2] + red[3];
        float mean = total / (float)((long long)BATCH * HH * WW);
        out[0] = fabsf(1.0f - mean);
    }
}

extern "C" void kernel_launch(void* const* d_in, const int* in_sizes, int n_in,
                              void* d_out, int out_size, void* d_ws, size_t ws_size,
                              hipStream_t stream) {
    const float* x = (const float*)d_in[0];
    float* out = (float*)d_out;

    __half* hm = (__half*)d_ws;                                   // 16.78 MB
    float* partials = (float*)((char*)d_ws + (size_t)BATCH * CH * 2);  // 1024 f32

    // K1: 32*512*32 threads = 2048 blocks
    hmin_kernel<<<2048, 256, 0, stream>>>(x, hm);
    // K2: 32*32*256 threads = 1024 blocks
    vmin_kernel<<<1024, 256, 0, stream>>>((const unsigned*)hm, partials);
    dark_reduce_kernel<<<1, 256, 0, stream>>>(partials, 1024, out);
}